// Round 13
// baseline (121.031 us; speedup 1.0000x reference)
//
#include <hip/hip_runtime.h>
#include <math.h>
#include <stdint.h>

#define NPROJ 16
#define NP8 8                 // projections per block (split across block pairs)
#define NBINS 65536
#define WD (NBINS - 6)
#define BMW 2056              // bitmap u32 words per bp (8224 B); bit k = old byte k
#define B_ 2
#define C_ 3
#define H_ 384
#define W_ 384
#define HO 378
#define NPAT (HO * HO)        // 142884 (div by 4)
#define DF 147                // 3*7*7
#define BP 32                 // B_*NPROJ
#define TSTR 24               // LDS tile row stride -> uniform 2-way (free)

__device__ inline unsigned f2key(float f) {
    unsigned u = __float_as_uint(f);
    return (u & 0x80000000u) ? ~u : (u | 0x80000000u);
}
__device__ inline float key2f(unsigned k) {
    unsigned u = (k & 0x80000000u) ? (k ^ 0x80000000u) : ~k;
    return __uint_as_float(u);
}

// ---------- K0: rand/std (ddof=1); init keys; zero out + bitmap --------------
__global__ __launch_bounds__(64) void k_rnorm(const float* __restrict__ rnd,
                                              float* __restrict__ rnorm,
                                              unsigned* __restrict__ keys,
                                              unsigned* __restrict__ bitmap,
                                              float* __restrict__ out) {
    int bp = blockIdx.x;
    int b = bp / NPROJ, p = bp % NPROJ;
    int lane = threadIdx.x;
    if (lane == 0) {
        keys[2 * bp] = 0xFFFFFFFFu;
        keys[2 * bp + 1] = 0u;
        if (bp == 0) out[0] = 0.f;     // accumulated atomically in k_gather
    }
    // zero the bitmap (replaces hipMemsetAsync); re-done every call
    for (int i = bp * 64 + lane; i < BP * BMW; i += BP * 64)
        bitmap[i] = 0u;

    float s = 0.f, s2 = 0.f;
    for (int d = lane; d < DF; d += 64) {
        float v = rnd[((size_t)b * DF + d) * NPROJ + p];
        s += v; s2 += v * v;
    }
    for (int o = 32; o > 0; o >>= 1) { s += __shfl_down(s, o); s2 += __shfl_down(s2, o); }
    s = __shfl(s, 0); s2 = __shfl(s2, 0);
    float mean = s / (float)DF;
    float var = (s2 - (float)DF * mean * mean) / (float)(DF - 1);
    float inv = 1.0f / sqrtf(var);
    for (int d = lane; d < DF; d += 64) {
        size_t idx = ((size_t)b * DF + d) * NPROJ + p;
        rnorm[idx] = rnd[idx] * inv;
    }
}

// ---------- K1: proj both images; store px AND py; min/max atomics -----------
// tile 32(h)x16(w), 256 threads, 2 outputs/thread, 8 projections/block.
// grid (48,12,4): x = tile_x*2 + proj_group, z = b*2 + isy.
// Weights via wave-uniform s_load (SGPR operands).
#define T1H 32
#define T1W 16
__global__ __launch_bounds__(256) void k_projmm(const float* __restrict__ ximg,
                                                const float* __restrict__ yimg,
                                                const float* __restrict__ rnorm,
                                                float* __restrict__ px,
                                                float* __restrict__ py,
                                                unsigned* __restrict__ keys) {
    __shared__ float tile[C_][T1H + 6][TSTR];   // [3][38][24]
    __shared__ float red_mn[4][NP8], red_mx[4][NP8];
    int bz = blockIdx.z;
    int b = bz >> 1, isy = bz & 1;
    int pg = blockIdx.x & 1;                    // projection group (0 or 1)
    int po = pg * NP8;
    int bx = blockIdx.x >> 1;
    const float* img = isy ? yimg : ximg;
    float* proj = isy ? py : px;
    int tid = threadIdx.x;
    int tx = tid & 15, ty = tid >> 4;              // 16x16 threads, rows 16 apart
    int h0 = blockIdx.y * T1H, w0 = bx * T1W;

    for (int c = 0; c < C_; c++)
        for (int i = tid; i < (T1H + 6) * (T1W + 6); i += 256) {
            int r = i / (T1W + 6), col = i % (T1W + 6);
            int h = h0 + r, w = w0 + col;
            tile[c][r][col] = (h < H_ && w < W_)
                ? img[((size_t)(b * C_ + c) * H_ + h) * W_ + w] : 0.f;
        }
    __syncthreads();

    const float* wbase = rnorm + (size_t)b * DF * NPROJ + po;

    float acc[2][NP8];
#pragma unroll
    for (int q = 0; q < 2; q++)
#pragma unroll
        for (int p = 0; p < NP8; p++) acc[q][p] = 0.f;

    for (int c = 0; c < C_; c++)
        for (int i = 0; i < 7; i++)
#pragma unroll
            for (int j = 0; j < 7; j++) {
                const float* wrow = wbase + (c * 49 + i * 7 + j) * NPROJ; // uniform
                float wv[NP8];
#pragma unroll
                for (int p = 0; p < NP8; p++) wv[p] = wrow[p];            // s_load
                float pix0 = tile[c][ty + i][tx + j];
                float pix1 = tile[c][ty + 16 + i][tx + j];
#pragma unroll
                for (int p = 0; p < NP8; p++) {
                    acc[0][p] = fmaf(pix0, wv[p], acc[0][p]);
                    acc[1][p] = fmaf(pix1, wv[p], acc[1][p]);
                }
            }

    int wo = w0 + tx;
    int ho0 = h0 + ty, ho1 = h0 + ty + 16;
    bool vm0 = (ho0 < HO) && (wo < HO);
    bool vm1 = (ho1 < HO) && (wo < HO);

    if (vm0) {
        size_t n = (size_t)ho0 * HO + wo;
#pragma unroll
        for (int p = 0; p < NP8; p++)
            proj[((size_t)(b * NPROJ + po + p)) * NPAT + n] = acc[0][p];
    }
    if (vm1) {
        size_t n = (size_t)ho1 * HO + wo;
#pragma unroll
        for (int p = 0; p < NP8; p++)
            proj[((size_t)(b * NPROJ + po + p)) * NPAT + n] = acc[1][p];
    }

    float pmn[NP8], pmx[NP8];
#pragma unroll
    for (int p = 0; p < NP8; p++) {
        float mn = INFINITY, mx = -INFINITY;
        if (vm0) { mn = acc[0][p]; mx = acc[0][p]; }
        if (vm1) { mn = fminf(mn, acc[1][p]); mx = fmaxf(mx, acc[1][p]); }
        pmn[p] = mn; pmx[p] = mx;
    }
#pragma unroll
    for (int o = 1; o < 64; o <<= 1) {
#pragma unroll
        for (int p = 0; p < NP8; p++) {
            pmn[p] = fminf(pmn[p], __shfl_xor(pmn[p], o));
            pmx[p] = fmaxf(pmx[p], __shfl_xor(pmx[p], o));
        }
    }
    int wv4 = tid >> 6;
    if ((tid & 63) == 0) {
#pragma unroll
        for (int p = 0; p < NP8; p++) { red_mn[wv4][p] = pmn[p]; red_mx[wv4][p] = pmx[p]; }
    }
    __syncthreads();
    if (tid < NP8) {
        float mn = fminf(fminf(red_mn[0][tid], red_mn[1][tid]),
                         fminf(red_mn[2][tid], red_mn[3][tid]));
        float mx = fmaxf(fmaxf(red_mx[0][tid], red_mx[1][tid]),
                         fmaxf(red_mx[2][tid], red_mx[3][tid]));
        atomicMin(&keys[2 * (b * NPROJ + po + tid)], f2key(mn));
        atomicMax(&keys[2 * (b * NPROJ + po + tid) + 1], f2key(mx));
    }
}

// ---------- K2: y-hist scatter -> LDS bitmap, one atomicOr flush -------------
__global__ __launch_bounds__(256) void k_scatter(const float* __restrict__ py,
                                                 const unsigned* __restrict__ keys,
                                                 unsigned* __restrict__ bitmap) {
    __shared__ unsigned lbm[BMW];
    int bp = blockIdx.y;
    int tid = threadIdx.x;
    for (int i = tid; i < BMW; i += 256) lbm[i] = 0u;
    __syncthreads();

    float mn = key2f(keys[2 * bp]);
    float sc = key2f(keys[2 * bp + 1]) - mn;
    const float4* src = (const float4*)(py + (size_t)bp * NPAT);
    const int n4 = NPAT / 4;
    for (int i = blockIdx.x * blockDim.x + tid; i < n4;
         i += gridDim.x * blockDim.x) {
        float4 v = src[i];
        float vv[4] = { v.x, v.y, v.z, v.w };
#pragma unroll
        for (int j = 0; j < 4; j++) {
            int idx = (int)floorf(65535.f * (vv[j] - mn) / sc);
            int bit = 8 + min(max(idx, 0), 65535);
            atomicOr(&lbm[bit >> 5], 1u << (bit & 31));
        }
    }
    __syncthreads();
    unsigned* dst = bitmap + (size_t)bp * BMW;
    for (int i = tid; i < BMW; i += 256) {
        unsigned w = lbm[i];
        if (w) atomicOr(&dst[i], w);
    }
}

// ---------- K3: gather via LDS-staged bitmap + 256-entry LDS LUT -------------
__global__ __launch_bounds__(256) void k_gather(const float* __restrict__ px,
                                                const unsigned* __restrict__ keys,
                                                const unsigned* __restrict__ bitmap,
                                                float* __restrict__ out) {
    __shared__ unsigned lbm[BMW];
    __shared__ float2 lut[256];
    __shared__ float sred[4];
    int bp = blockIdx.y;
    int tid = threadIdx.x;

    const unsigned* gbm = bitmap + (size_t)bp * BMW;
    for (int i = tid; i < BMW; i += 256) lbm[i] = gbm[i];

    float g[7];
#pragma unroll
    for (int k = 0; k < 7; k++) {
        float d = (float)(k - 3);
        g[k] = expf(-(d * d) / 1.44f);   // exp((x)^2/(-2*1.2^2))**2
    }
    {
        int m = tid;   // 256 threads -> one LUT entry each
        float f[8];
#pragma unroll
        for (int k = 0; k < 8; k++) f[k] = (float)((m >> k) & 1);
        float s0 = g[0] * f[0] + g[1] * f[1] + g[2] * f[2] + g[3] * f[3]
                 + g[4] * f[4] + g[5] * f[5] + g[6] * f[6];
        float s1 = g[0] * f[1] + g[1] * f[2] + g[2] * f[3] + g[3] * f[4]
                 + g[4] * f[5] + g[5] * f[6] + g[6] * f[7];
        lut[m] = make_float2(fminf(s0, 1.f), fminf(s1, 1.f));
    }
    __syncthreads();

    float mn = key2f(keys[2 * bp]);
    float sc = key2f(keys[2 * bp + 1]) - mn;
    const float4* src = (const float4*)(px + (size_t)bp * NPAT);

    float acc = 0.f;
    const int n4 = NPAT / 4;
    for (int i = blockIdx.x * blockDim.x + tid; i < n4;
         i += gridDim.x * blockDim.x) {
        float4 v4 = src[i];
        float vv[4] = { v4.x, v4.y, v4.z, v4.w };
#pragma unroll
        for (int j = 0; j < 4; j++) {
            float v = vv[j];
            float t = (v - mn) / sc;             // in [0,1]
            float ix = t * (float)WD - 0.5f;
            float x0 = floorf(ix);
            float w1 = ix - x0;
            int x0i = (int)x0;                   // [-1, WD-1]
            int bit0 = 8 + x0i;                  // [7, 65536]
            int w = bit0 >> 5, s = bit0 & 31;
            uint64_t d = (uint64_t)lbm[w] | ((uint64_t)lbm[w + 1] << 32);
            uint32_t w8 = (uint32_t)(d >> s) & 0xFFu;
            float2 sv = lut[w8];
            float r0 = (x0i >= 0) ? sv.x : 0.f;
            float r1 = (x0i + 1 < WD) ? sv.y : 0.f;
            acc += r0 * (1.f - w1) + r1 * w1;
        }
    }
    for (int o = 32; o > 0; o >>= 1) acc += __shfl_down(acc, o);
    int wv4 = tid >> 6;
    if ((tid & 63) == 0) sred[wv4] = acc;
    __syncthreads();
    if (tid == 0) {
        float t = sred[0] + sred[1] + sred[2] + sred[3];
        atomicAdd(out, -t * (1.0f / 32.0f));
    }
}

extern "C" void kernel_launch(void* const* d_in, const int* in_sizes, int n_in,
                              void* d_out, int out_size, void* d_ws, size_t ws_size,
                              hipStream_t stream) {
    (void)in_sizes; (void)n_in; (void)out_size; (void)ws_size;
    const float* x = (const float*)d_in[0];
    const float* y = (const float*)d_in[1];
    const float* rnd = (const float*)d_in[2];
    float* out = (float*)d_out;

    float* ws = (float*)d_ws;
    float* rnorm = ws;                                     // 4704 floats
    float* px = rnorm + (size_t)B_ * DF * NPROJ;           // BP*NPAT floats
    float* py = px + (size_t)BP * NPAT;                    // BP*NPAT floats
    unsigned* keys = (unsigned*)(py + (size_t)BP * NPAT);  // 2*BP
    unsigned* bitmap = keys + 2 * BP;                      // BP*BMW u32 (263 KB)

    k_rnorm<<<BP, 64, 0, stream>>>(rnd, rnorm, keys, bitmap, out);

    dim3 g1(2 * (384 / T1W), 384 / T1H, 2 * B_);           // (48,12,4)
    k_projmm<<<g1, 256, 0, stream>>>(x, y, rnorm, px, py, keys);

    k_scatter<<<dim3(16, BP), 256, 0, stream>>>(py, keys, bitmap);
    k_gather<<<dim3(70, BP), 256, 0, stream>>>(px, keys, bitmap, out);
}

// Round 14
// 105.070 us; speedup vs baseline: 1.1519x; 1.1519x over previous
//
#include <hip/hip_runtime.h>
#include <math.h>
#include <stdint.h>

#define NPROJ 16
#define NBINS 65536
#define WD (NBINS - 6)
#define BMW 2056              // bitmap u32 words per bp (8224 B); bit k = old byte k
#define B_ 2
#define C_ 3
#define H_ 384
#define W_ 384
#define HO 378
#define NPAT (HO * HO)        // 142884 (div by 4)
#define DF 147                // 3*7*7
#define BP 32                 // B_*NPROJ

__device__ inline unsigned f2key(float f) {
    unsigned u = __float_as_uint(f);
    return (u & 0x80000000u) ? ~u : (u | 0x80000000u);
}
__device__ inline float key2f(unsigned k) {
    unsigned u = (k & 0x80000000u) ? (k ^ 0x80000000u) : ~k;
    return __uint_as_float(u);
}

// ---------- K0: rand/std (ddof=1); init keys; zero out + bitmap --------------
__global__ __launch_bounds__(64) void k_rnorm(const float* __restrict__ rnd,
                                              float* __restrict__ rnorm,
                                              unsigned* __restrict__ keys,
                                              unsigned* __restrict__ bitmap,
                                              float* __restrict__ out) {
    int bp = blockIdx.x;
    int b = bp / NPROJ, p = bp % NPROJ;
    int lane = threadIdx.x;
    if (lane == 0) {
        keys[2 * bp] = 0xFFFFFFFFu;
        keys[2 * bp + 1] = 0u;
        if (bp == 0) out[0] = 0.f;     // accumulated atomically in k_gather
    }
    // zero the bitmap (replaces hipMemsetAsync); re-done every call
    for (int i = bp * 64 + lane; i < BP * BMW; i += BP * 64)
        bitmap[i] = 0u;

    float s = 0.f, s2 = 0.f;
    for (int d = lane; d < DF; d += 64) {
        float v = rnd[((size_t)b * DF + d) * NPROJ + p];
        s += v; s2 += v * v;
    }
    for (int o = 32; o > 0; o >>= 1) { s += __shfl_down(s, o); s2 += __shfl_down(s2, o); }
    s = __shfl(s, 0); s2 = __shfl(s2, 0);
    float mean = s / (float)DF;
    float var = (s2 - (float)DF * mean * mean) / (float)(DF - 1);
    float inv = 1.0f / sqrtf(var);
    for (int d = lane; d < DF; d += 64) {
        size_t idx = ((size_t)b * DF + d) * NPROJ + p;
        rnorm[idx] = rnd[idx] * inv;
    }
}

// ---------- K1: proj both images; store px AND py; min/max atomics -----------
// 2 adjacent output COLS per thread: tile 32(w)x16(h), 256 threads (16x16),
// grid (12,24,4): z=b*2+isy. Pixels via 4x ds_read_b64 per (c,i) serving
// 224 FMA; weights via wave-uniform s_load (SGPR operands).
#define TW 32                 // output cols per tile
#define TH 16                 // output rows per tile
#define TSTR2 40              // LDS row stride (38 used), even -> 8B-aligned rows
__global__ __launch_bounds__(256) void k_projmm(const float* __restrict__ ximg,
                                                const float* __restrict__ yimg,
                                                const float* __restrict__ rnorm,
                                                float* __restrict__ px,
                                                float* __restrict__ py,
                                                unsigned* __restrict__ keys) {
    __shared__ float tile[C_][TH + 6][TSTR2];   // [3][22][40] = 10560 B
    __shared__ float red_mn[4][NPROJ], red_mx[4][NPROJ];
    int bz = blockIdx.z;
    int b = bz >> 1, isy = bz & 1;
    const float* img = isy ? yimg : ximg;
    float* proj = isy ? py : px;
    int tid = threadIdx.x;
    int tx = tid & 15, ty = tid >> 4;              // 16x16 threads
    int h0 = blockIdx.y * TH, w0 = blockIdx.x * TW;

    for (int c = 0; c < C_; c++)
        for (int i = tid; i < (TH + 6) * (TW + 6); i += 256) {
            int r = i / (TW + 6), col = i % (TW + 6);
            int h = h0 + r, w = w0 + col;
            tile[c][r][col] = (h < H_ && w < W_)
                ? img[((size_t)(b * C_ + c) * H_ + h) * W_ + w] : 0.f;
        }
    __syncthreads();

    const float* wbase = rnorm + (size_t)b * DF * NPROJ;

    float acc[2][NPROJ];                // [col 2tx, col 2tx+1]
#pragma unroll
    for (int q = 0; q < 2; q++)
#pragma unroll
        for (int p = 0; p < NPROJ; p++) acc[q][p] = 0.f;

    for (int c = 0; c < C_; c++)
        for (int i = 0; i < 7; i++) {
            float pxr[8];
            const float2* row = (const float2*)&tile[c][ty + i][2 * tx]; // 8B-aligned
#pragma unroll
            for (int q = 0; q < 4; q++) {
                float2 t2 = row[q];              // ds_read_b64
                pxr[2 * q] = t2.x; pxr[2 * q + 1] = t2.y;
            }
#pragma unroll
            for (int j = 0; j < 7; j++) {
                const float* wrow = wbase + (c * 49 + i * 7 + j) * NPROJ; // uniform
                float wv[NPROJ];
#pragma unroll
                for (int p = 0; p < NPROJ; p++) wv[p] = wrow[p];          // s_load
#pragma unroll
                for (int p = 0; p < NPROJ; p++) {
                    acc[0][p] = fmaf(pxr[j], wv[p], acc[0][p]);
                    acc[1][p] = fmaf(pxr[j + 1], wv[p], acc[1][p]);
                }
            }
        }

    int wo = w0 + 2 * tx;               // even; wo<HO  <=>  wo+1<HO (HO even)
    int ho = h0 + ty;
    bool vm = (ho < HO) && (wo < HO);

    if (vm) {
        size_t n = (size_t)ho * HO + wo;     // even -> 8B-aligned float2 store
#pragma unroll
        for (int p = 0; p < NPROJ; p++)
            *(float2*)&proj[((size_t)(b * NPROJ + p)) * NPAT + n] =
                make_float2(acc[0][p], acc[1][p]);
    }

    float pmn[NPROJ], pmx[NPROJ];
#pragma unroll
    for (int p = 0; p < NPROJ; p++) {
        float mn = INFINITY, mx = -INFINITY;
        if (vm) {
            mn = fminf(acc[0][p], acc[1][p]);
            mx = fmaxf(acc[0][p], acc[1][p]);
        }
        pmn[p] = mn; pmx[p] = mx;
    }
#pragma unroll
    for (int o = 1; o < 64; o <<= 1) {
#pragma unroll
        for (int p = 0; p < NPROJ; p++) {
            pmn[p] = fminf(pmn[p], __shfl_xor(pmn[p], o));
            pmx[p] = fmaxf(pmx[p], __shfl_xor(pmx[p], o));
        }
    }
    int wv4 = tid >> 6;
    if ((tid & 63) == 0) {
#pragma unroll
        for (int p = 0; p < NPROJ; p++) { red_mn[wv4][p] = pmn[p]; red_mx[wv4][p] = pmx[p]; }
    }
    __syncthreads();
    if (tid < NPROJ) {
        float mn = fminf(fminf(red_mn[0][tid], red_mn[1][tid]),
                         fminf(red_mn[2][tid], red_mn[3][tid]));
        float mx = fmaxf(fmaxf(red_mx[0][tid], red_mx[1][tid]),
                         fmaxf(red_mx[2][tid], red_mx[3][tid]));
        atomicMin(&keys[2 * (b * NPROJ + tid)], f2key(mn));
        atomicMax(&keys[2 * (b * NPROJ + tid) + 1], f2key(mx));
    }
}

// ---------- K2: y-hist scatter -> LDS bitmap, one atomicOr flush -------------
__global__ __launch_bounds__(256) void k_scatter(const float* __restrict__ py,
                                                 const unsigned* __restrict__ keys,
                                                 unsigned* __restrict__ bitmap) {
    __shared__ unsigned lbm[BMW];
    int bp = blockIdx.y;
    int tid = threadIdx.x;
    for (int i = tid; i < BMW; i += 256) lbm[i] = 0u;
    __syncthreads();

    float mn = key2f(keys[2 * bp]);
    float sc = key2f(keys[2 * bp + 1]) - mn;
    const float4* src = (const float4*)(py + (size_t)bp * NPAT);
    const int n4 = NPAT / 4;
    for (int i = blockIdx.x * blockDim.x + tid; i < n4;
         i += gridDim.x * blockDim.x) {
        float4 v = src[i];
        float vv[4] = { v.x, v.y, v.z, v.w };
#pragma unroll
        for (int j = 0; j < 4; j++) {
            int idx = (int)floorf(65535.f * (vv[j] - mn) / sc);
            int bit = 8 + min(max(idx, 0), 65535);
            atomicOr(&lbm[bit >> 5], 1u << (bit & 31));
        }
    }
    __syncthreads();
    unsigned* dst = bitmap + (size_t)bp * BMW;
    for (int i = tid; i < BMW; i += 256) {
        unsigned w = lbm[i];
        if (w) atomicOr(&dst[i], w);
    }
}

// ---------- K3: gather via LDS-staged bitmap + 256-entry LDS LUT -------------
__global__ __launch_bounds__(256) void k_gather(const float* __restrict__ px,
                                                const unsigned* __restrict__ keys,
                                                const unsigned* __restrict__ bitmap,
                                                float* __restrict__ out) {
    __shared__ unsigned lbm[BMW];
    __shared__ float2 lut[256];
    __shared__ float sred[4];
    int bp = blockIdx.y;
    int tid = threadIdx.x;

    const unsigned* gbm = bitmap + (size_t)bp * BMW;
    for (int i = tid; i < BMW; i += 256) lbm[i] = gbm[i];

    float g[7];
#pragma unroll
    for (int k = 0; k < 7; k++) {
        float d = (float)(k - 3);
        g[k] = expf(-(d * d) / 1.44f);   // exp((x)^2/(-2*1.2^2))**2
    }
    {
        int m = tid;   // 256 threads -> one LUT entry each
        float f[8];
#pragma unroll
        for (int k = 0; k < 8; k++) f[k] = (float)((m >> k) & 1);
        float s0 = g[0] * f[0] + g[1] * f[1] + g[2] * f[2] + g[3] * f[3]
                 + g[4] * f[4] + g[5] * f[5] + g[6] * f[6];
        float s1 = g[0] * f[1] + g[1] * f[2] + g[2] * f[3] + g[3] * f[4]
                 + g[4] * f[5] + g[5] * f[6] + g[6] * f[7];
        lut[m] = make_float2(fminf(s0, 1.f), fminf(s1, 1.f));
    }
    __syncthreads();

    float mn = key2f(keys[2 * bp]);
    float sc = key2f(keys[2 * bp + 1]) - mn;
    const float4* src = (const float4*)(px + (size_t)bp * NPAT);

    float acc = 0.f;
    const int n4 = NPAT / 4;
    for (int i = blockIdx.x * blockDim.x + tid; i < n4;
         i += gridDim.x * blockDim.x) {
        float4 v4 = src[i];
        float vv[4] = { v4.x, v4.y, v4.z, v4.w };
#pragma unroll
        for (int j = 0; j < 4; j++) {
            float v = vv[j];
            float t = (v - mn) / sc;             // in [0,1]
            float ix = t * (float)WD - 0.5f;
            float x0 = floorf(ix);
            float w1 = ix - x0;
            int x0i = (int)x0;                   // [-1, WD-1]
            int bit0 = 8 + x0i;                  // [7, 65536]
            int w = bit0 >> 5, s = bit0 & 31;
            uint64_t d = (uint64_t)lbm[w] | ((uint64_t)lbm[w + 1] << 32);
            uint32_t w8 = (uint32_t)(d >> s) & 0xFFu;
            float2 sv = lut[w8];
            float r0 = (x0i >= 0) ? sv.x : 0.f;
            float r1 = (x0i + 1 < WD) ? sv.y : 0.f;
            acc += r0 * (1.f - w1) + r1 * w1;
        }
    }
    for (int o = 32; o > 0; o >>= 1) acc += __shfl_down(acc, o);
    int wv4 = tid >> 6;
    if ((tid & 63) == 0) sred[wv4] = acc;
    __syncthreads();
    if (tid == 0) {
        float t = sred[0] + sred[1] + sred[2] + sred[3];
        atomicAdd(out, -t * (1.0f / 32.0f));
    }
}

extern "C" void kernel_launch(void* const* d_in, const int* in_sizes, int n_in,
                              void* d_out, int out_size, void* d_ws, size_t ws_size,
                              hipStream_t stream) {
    (void)in_sizes; (void)n_in; (void)out_size; (void)ws_size;
    const float* x = (const float*)d_in[0];
    const float* y = (const float*)d_in[1];
    const float* rnd = (const float*)d_in[2];
    float* out = (float*)d_out;

    float* ws = (float*)d_ws;
    float* rnorm = ws;                                     // 4704 floats
    float* px = rnorm + (size_t)B_ * DF * NPROJ;           // BP*NPAT floats
    float* py = px + (size_t)BP * NPAT;                    // BP*NPAT floats
    unsigned* keys = (unsigned*)(py + (size_t)BP * NPAT);  // 2*BP
    unsigned* bitmap = keys + 2 * BP;                      // BP*BMW u32 (263 KB)

    k_rnorm<<<BP, 64, 0, stream>>>(rnd, rnorm, keys, bitmap, out);

    dim3 g1(384 / TW, 384 / TH, 2 * B_);                   // (12,24,4)
    k_projmm<<<g1, 256, 0, stream>>>(x, y, rnorm, px, py, keys);

    k_scatter<<<dim3(16, BP), 256, 0, stream>>>(py, keys, bitmap);
    k_gather<<<dim3(70, BP), 256, 0, stream>>>(px, keys, bitmap, out);
}